// Round 1
// baseline (154.379 us; speedup 1.0000x reference)
//
#include <hip/hip_runtime.h>
#include <math.h>

// densityPropGRUCell on MI355X (gfx950).
// B=128, U=D=256. Dominant cost: 3x batched W^T S W (25.8 GFLOP) -> bf16 MFMA.
// Pipeline: prep (cvt S->bf16, W->W^T bf16, gate vectors/scalars)
//           gateZ  (Sigma_z = (W_z^T S W_z + diag) .* gz gz^T)        -> ws f32
//           gateR  (sigma_g from Sigma_r, S, prev, r; trace partials) -> ws bf16
//           gateH  (Sigma_hh -> Sigma_h -> Sigma_out fused epilogue)  -> d_out

typedef __attribute__((ext_vector_type(8))) short sh8;           // 8 x bf16 fragment
typedef __attribute__((ext_vector_type(4))) float f4;            // MFMA acc
typedef __attribute__((ext_vector_type(4))) unsigned short us4;  // 4 x bf16 pack

__device__ __forceinline__ unsigned short f2bf(float f) {
  unsigned int u = __float_as_uint(f);
  u = (u + 0x7fffu + ((u >> 16) & 1u)) >> 16;  // RNE
  return (unsigned short)u;
}

__device__ __forceinline__ f4 mfma16(sh8 a, sh8 b, f4 c) {
  return __builtin_amdgcn_mfma_f32_16x16x32_bf16(a, b, c, 0, 0, 0);
}

// ---------------------------------------------------------------------------
// prep kernel. Grid layout:
//   blocks [0,2048)     : Sigma_state f32 -> bf16 (Sbf), 16 floats/thread
//   blocks [2048,2051)  : WT_g[n][k] = bf16(W_g[k][n])   (one block per gate)
//   blocks [2051,2179)  : per-batch gates z,r,h + scalars + mu_out (one block/batch)
// ---------------------------------------------------------------------------
__global__ __launch_bounds__(256) void prep_kernel(
    const float* __restrict__ xin, const float* __restrict__ prev,
    const float* __restrict__ S,
    const float* __restrict__ Uz, const float* __restrict__ uzs,
    const float* __restrict__ Wz, const float* __restrict__ wzs,
    const float* __restrict__ Ur, const float* __restrict__ urs,
    const float* __restrict__ Wr, const float* __restrict__ wrs,
    const float* __restrict__ Uh, const float* __restrict__ uhs,
    const float* __restrict__ Wh, const float* __restrict__ whs,
    unsigned short* __restrict__ Sbf,
    unsigned short* __restrict__ WTz, unsigned short* __restrict__ WTr,
    unsigned short* __restrict__ WTh,
    float* __restrict__ gzv, float* __restrict__ grv, float* __restrict__ ghv,
    float* __restrict__ zv, float* __restrict__ rv, float* __restrict__ pmhv,
    float* __restrict__ diagz, float* __restrict__ diagr,
    float* __restrict__ sphw, float* __restrict__ sphu,
    float* __restrict__ sxA, float* __restrict__ ssrA,
    float* __restrict__ muOut)
{
  const int blk = blockIdx.x, t = threadIdx.x;

  if (blk < 2048) {  // ---- S -> bf16 ----
    const f4* S4 = (const f4*)S;
    us4* O4 = (us4*)Sbf;
    const int base = blk * 256 + t;
#pragma unroll
    for (int i = 0; i < 4; ++i) {
      int idx = base + i * 524288;   // 2048*256 float4s per sweep
      f4 v = S4[idx];
      us4 o;
      o[0] = f2bf(v[0]); o[1] = f2bf(v[1]); o[2] = f2bf(v[2]); o[3] = f2bf(v[3]);
      O4[idx] = o;
    }
    return;
  }

  if (blk < 2051) {  // ---- W transpose to bf16 ----
    const int g = blk - 2048;
    const float* W = (g == 0) ? Wz : ((g == 1) ? Wr : Wh);
    unsigned short* WT = (g == 0) ? WTz : ((g == 1) ? WTr : WTh);
    for (int n = 0; n < 256; ++n)
      WT[n * 256 + t] = f2bf(W[t * 256 + n]);  // coalesced writes
    return;
  }

  // ---- per-batch gate math ----
  const int b = blk - 2051;
  __shared__ float xs[256], ps[256], srs[256];
  __shared__ float red[4];

  auto bred = [&](float v) -> float {  // block-wide sum over 256 threads
#pragma unroll
    for (int off = 32; off; off >>= 1) v += __shfl_down(v, off, 64);
    __syncthreads();
    if ((t & 63) == 0) red[t >> 6] = v;
    __syncthreads();
    return red[0] + red[1] + red[2] + red[3];
  };

  xs[t] = xin[b * 256 + t];
  ps[t] = prev[b * 256 + t];
  __syncthreads();

  float mz = 0.f, mr = 0.f;
  for (int d = 0; d < 256; ++d) {
    float xd = xs[d];
    mz = fmaf(xd, Uz[d * 256 + t], mz);
    mr = fmaf(xd, Ur[d * 256 + t], mr);
  }
  for (int j = 0; j < 256; ++j) {
    float pj = ps[j];
    mz = fmaf(pj, Wz[j * 256 + t], mz);
    mr = fmaf(pj, Wr[j * 256 + t], mr);
  }
  float z = 1.f / (1.f + expf(-mz));
  float r = 1.f / (1.f + expf(-mr));
  srs[t] = ps[t] * r;
  __syncthreads();

  float mh = 0.f;
  for (int d = 0; d < 256; ++d) mh = fmaf(xs[d], Uh[d * 256 + t], mh);
  for (int j = 0; j < 256; ++j) mh = fmaf(srs[j], Wh[j * 256 + t], mh);
  float h = tanhf(mh);

  float sx  = bred(xs[t] * xs[t]);
  float sp  = bred(ps[t] * ps[t]);
  float ssr = bred(srs[t] * srs[t]);
  float trS = bred(S[(size_t)b * 65536 + t * 257]);

  float spwz = log1pf(expf(wzs[t])), spuz = log1pf(expf(uzs[t]));
  float spwr = log1pf(expf(wrs[t])), spur = log1pf(expf(urs[t]));

  const int idx = b * 256 + t;
  gzv[idx]  = z * (1.f - z);
  grv[idx]  = r * (1.f - r);
  ghv[idx]  = 1.f - h * h;
  zv[idx]   = z;
  rv[idx]   = r;
  pmhv[idx] = ps[t] - h;
  diagz[idx] = (sp + trS) * spwz + sx * spuz;
  diagr[idx] = (sp + trS) * spwr + sx * spur;
  muOut[idx] = z * ps[t] + (1.f - z) * h;
  if (b == 0) { sphw[t] = log1pf(expf(whs[t])); sphu[t] = log1pf(expf(uhs[t])); }
  if (t == 0) { sxA[b] = sx; ssrA[b] = ssr; }
}

// ---------------------------------------------------------------------------
// Fused Y = W^T (A W) per (batch, 64-col block) with gate-specific epilogue.
// GATE 0 (z): fOut = Sigma_z (ws f32)
// GATE 1 (r): sgOut = sigma_g (ws bf16), trsgOut[b*4+nb] = partial trace
// GATE 2 (h): fOut = Sigma_out (d_out)
// Fragment maps: A row = lane&15, B col = lane&15, k = kt*32 + 8*(lane>>4) + e.
// (k-map need only be a consistent bijection between A and B; C/D map is the
//  HW-verified col=lane&15, row=4*(lane>>4)+reg.)
// ---------------------------------------------------------------------------
template <int GATE>
__global__ __launch_bounds__(256) void gate_kernel(
    const unsigned short* __restrict__ Amat,  // [B][256][256] bf16
    const unsigned short* __restrict__ WT,    // [256][256] bf16, WT[n][k]=W[k][n]
    const float* __restrict__ S,              // Sigma_state f32 (R,H)
    const float* __restrict__ Sz,             // Sigma_z f32 (H)
    const float* __restrict__ v1,             // gz / gr / gh
    const float* __restrict__ dvec,           // diagz / diagr / -
    const float* __restrict__ v2,             // -  / prev / z
    const float* __restrict__ v3,             // -  / r    / (prev-h)
    const float* __restrict__ sxA, const float* __restrict__ ssrA,
    const float* __restrict__ trsgIn,         // (H) partials [B*4]
    const float* __restrict__ sphw, const float* __restrict__ sphu,
    float* __restrict__ fOut,
    unsigned short* __restrict__ sgOut,
    float* __restrict__ trsgOut)
{
  __shared__ unsigned short Tt[64][264];  // T^T, padded: row stride 528B
  __shared__ float ev0[256], ev1[256], ev2[256], ev3[256];

  const int b = blockIdx.x >> 2, nb = blockIdx.x & 3;
  const int tid = threadIdx.x;
  const int wave = tid >> 6, lane = tid & 63, lhi = lane >> 4, l15 = lane & 15;
  const int col0 = nb * 64;
  const size_t bb = (size_t)b << 16;

  {  // epilogue vectors
    const int u = tid;
    ev0[u] = v1[b * 256 + u];
    if constexpr (GATE == 0) { ev1[u] = dvec[b * 256 + u]; }
    if constexpr (GATE == 1) {
      ev1[u] = dvec[b * 256 + u];
      ev2[u] = v2[b * 256 + u];
      ev3[u] = v3[b * 256 + u];
    }
    if constexpr (GATE == 2) {
      float trsg = trsgIn[b * 4] + trsgIn[b * 4 + 1] + trsgIn[b * 4 + 2] + trsgIn[b * 4 + 3];
      ev1[u] = (ssrA[b] + trsg) * sphw[u] + sxA[b] * sphu[u];
      ev2[u] = v2[b * 256 + u];
      ev3[u] = v3[b * 256 + u];
    }
  }

  f4 acc[4][4];
  const f4 zero4 = {0.f, 0.f, 0.f, 0.f};
#pragma unroll
  for (int i = 0; i < 4; ++i)
#pragma unroll
    for (int j = 0; j < 4; ++j) acc[i][j] = zero4;

  // ---------------- stage 1: T = A_b @ W[:,col0:col0+64] ----------------
  const unsigned short* Ab = Amat + bb;
  const int kb = lhi * 8;
#pragma unroll
  for (int kt = 0; kt < 8; ++kt) {
    const int k = kt * 32 + kb;
    sh8 af[4], bfr[4];
#pragma unroll
    for (int rt = 0; rt < 4; ++rt)
      af[rt] = *reinterpret_cast<const sh8*>(Ab + ((wave * 64 + rt * 16 + l15) << 8) + k);
#pragma unroll
    for (int ct = 0; ct < 4; ++ct)
      bfr[ct] = *reinterpret_cast<const sh8*>(WT + ((col0 + ct * 16 + l15) << 8) + k);
#pragma unroll
    for (int rt = 0; rt < 4; ++rt)
#pragma unroll
      for (int ct = 0; ct < 4; ++ct)
        acc[rt][ct] = mfma16(af[rt], bfr[ct], acc[rt][ct]);
  }

  // write T^T (bf16) to LDS
#pragma unroll
  for (int rt = 0; rt < 4; ++rt) {
    const int row0 = wave * 64 + rt * 16 + lhi * 4;
#pragma unroll
    for (int ct = 0; ct < 4; ++ct) {
      const int c = ct * 16 + l15;
      us4 p;
      p[0] = f2bf(acc[rt][ct][0]); p[1] = f2bf(acc[rt][ct][1]);
      p[2] = f2bf(acc[rt][ct][2]); p[3] = f2bf(acc[rt][ct][3]);
      *reinterpret_cast<us4*>(&Tt[c][row0]) = p;
    }
  }
  __syncthreads();

#pragma unroll
  for (int i = 0; i < 4; ++i)
#pragma unroll
    for (int j = 0; j < 4; ++j) acc[i][j] = zero4;

  // ---------------- stage 2: Y = W^T @ T ----------------
#pragma unroll
  for (int jt = 0; jt < 8; ++jt) {
    const int j = jt * 32 + kb;
    sh8 af[4], bfr[4];
#pragma unroll
    for (int rt = 0; rt < 4; ++rt)
      af[rt] = *reinterpret_cast<const sh8*>(WT + ((wave * 64 + rt * 16 + l15) << 8) + j);
#pragma unroll
    for (int ct = 0; ct < 4; ++ct)
      bfr[ct] = *reinterpret_cast<const sh8*>(&Tt[ct * 16 + l15][j]);
#pragma unroll
    for (int rt = 0; rt < 4; ++rt)
#pragma unroll
      for (int ct = 0; ct < 4; ++ct)
        acc[rt][ct] = mfma16(af[rt], bfr[ct], acc[rt][ct]);
  }

  // ---------------- epilogue ----------------
  float trloc = 0.f;
#pragma unroll
  for (int rt = 0; rt < 4; ++rt) {
    const int i0 = wave * 64 + rt * 16 + lhi * 4;
#pragma unroll
    for (int ct = 0; ct < 4; ++ct) {
      const int j = col0 + ct * 16 + l15;
#pragma unroll
      for (int rr = 0; rr < 4; ++rr) {
        const int i = i0 + rr;
        const float y = acc[rt][ct][rr];
        const size_t idx = bb + ((size_t)i << 8) + j;
        if constexpr (GATE == 0) {
          float yv = y + ((i == j) ? ev1[i] : 0.f);
          fOut[idx] = yv * ev0[i] * ev0[j];
        } else if constexpr (GATE == 1) {
          float Sr = (y + ((i == j) ? ev1[i] : 0.f)) * ev0[i] * ev0[j];
          float Sv = S[idx];
          float sg = Sr * (Sv + ev2[i] * ev2[j]) + ev3[i] * ev3[j] * Sv;
          sgOut[idx] = f2bf(sg);
          if (i == j) trloc += sg;
        } else {
          float Sh = (y + ((i == j) ? ev1[i] : 0.f)) * ev0[i] * ev0[j];
          float Sv = S[idx];
          float Szv = Sz[idx];
          fOut[idx] = Szv * (Sv + Sh + ev3[i] * ev3[j])
                    + Sv * ev2[i] * ev2[j]
                    + Sh * (1.f - ev2[i]) * (1.f - ev2[j]);
        }
      }
    }
  }

  if constexpr (GATE == 1) {  // deterministic trace partial (no atomics)
    if (wave == nb) {
#pragma unroll
      for (int off = 32; off; off >>= 1) trloc += __shfl_down(trloc, off, 64);
      if (lane == 0) trsgOut[b * 4 + nb] = trloc;
    }
  }
}

// ---------------------------------------------------------------------------
extern "C" void kernel_launch(void* const* d_in, const int* in_sizes, int n_in,
                              void* d_out, int out_size, void* d_ws, size_t ws_size,
                              hipStream_t stream)
{
  const float* xin  = (const float*)d_in[0];
  const float* prev = (const float*)d_in[1];
  const float* S    = (const float*)d_in[2];
  const float* Uz = (const float*)d_in[3];  const float* uzs = (const float*)d_in[4];
  const float* Wz = (const float*)d_in[5];  const float* wzs = (const float*)d_in[6];
  const float* Ur = (const float*)d_in[7];  const float* urs = (const float*)d_in[8];
  const float* Wr = (const float*)d_in[9];  const float* wrs = (const float*)d_in[10];
  const float* Uh = (const float*)d_in[11]; const float* uhs = (const float*)d_in[12];
  const float* Wh = (const float*)d_in[13]; const float* whs = (const float*)d_in[14];

  float* muOut  = (float*)d_out;
  float* SigOut = muOut + 128 * 256;

  char* p = (char*)d_ws;
  auto take = [&](size_t bytes) { void* q = (void*)p; p += bytes; return q; };
  unsigned short* Sbf = (unsigned short*)take(16777216);  // S bf16
  unsigned short* sg  = (unsigned short*)take(16777216);  // sigma_g bf16
  float* SzBuf = (float*)take(33554432);                  // Sigma_z f32
  unsigned short* WTz = (unsigned short*)take(131072);
  unsigned short* WTr = (unsigned short*)take(131072);
  unsigned short* WTh = (unsigned short*)take(131072);
  float* gzv   = (float*)take(131072);
  float* grv   = (float*)take(131072);
  float* ghv   = (float*)take(131072);
  float* zv    = (float*)take(131072);
  float* rv    = (float*)take(131072);
  float* pmhv  = (float*)take(131072);
  float* diagz = (float*)take(131072);
  float* diagr = (float*)take(131072);
  float* sphw  = (float*)take(1024);
  float* sphu  = (float*)take(1024);
  float* sxA   = (float*)take(512);
  float* ssrA  = (float*)take(512);
  float* trsgP = (float*)take(2048);
  (void)in_sizes; (void)n_in; (void)out_size; (void)ws_size;

  prep_kernel<<<2179, 256, 0, stream>>>(
      xin, prev, S, Uz, uzs, Wz, wzs, Ur, urs, Wr, wrs, Uh, uhs, Wh, whs,
      Sbf, WTz, WTr, WTh, gzv, grv, ghv, zv, rv, pmhv, diagz, diagr,
      sphw, sphu, sxA, ssrA, muOut);

  gate_kernel<0><<<512, 256, 0, stream>>>(
      Sbf, WTz, nullptr, nullptr, gzv, diagz, nullptr, nullptr,
      sxA, ssrA, nullptr, sphw, sphu, SzBuf, nullptr, nullptr);

  gate_kernel<1><<<512, 256, 0, stream>>>(
      Sbf, WTr, S, nullptr, grv, diagr, prev, rv,
      sxA, ssrA, nullptr, sphw, sphu, nullptr, sg, trsgP);

  gate_kernel<2><<<512, 256, 0, stream>>>(
      sg, WTh, S, SzBuf, ghv, nullptr, zv, pmhv,
      sxA, ssrA, trsgP, sphw, sphu, SigOut, nullptr, nullptr);
}